// Round 9
// baseline (4337.447 us; speedup 1.0000x reference)
//
#include <hip/hip_runtime.h>

#define NB 64      // batch
#define NL 512     // seq len
#define NT 64      // answer len
#define NH 512     // hidden
#define NE 256     // emb dim
#define NW 256     // attention weight dim
#define NBNH (NB * NH)
#define RS 16      // h-ring depth (slots); phase stamp = (t>>4)&1

typedef __attribute__((ext_vector_type(8))) short bf16x8;
typedef __attribute__((ext_vector_type(4))) float f32x4;
typedef unsigned short u16;
typedef unsigned int u32;
typedef unsigned long long u64;

#define STM 0x4000400040004000ull   // bit14 of each u16 (never set in bf16 of |v|<2)
#define CLRM 0xBFFFBFFFBFFFBFFFull

__device__ __forceinline__ float bf2f(u16 v){
  union { u32 u; float f; } x; x.u = ((u32)v) << 16; return x.f;
}
__device__ __forceinline__ u16 f2bf(float f){
  union { float f; u32 u; } x; x.f = f;
  return (u16)((x.u + 0x7FFFu + ((x.u >> 16) & 1u)) >> 16);
}
__device__ __forceinline__ float sigm(float x){ return 1.f / (1.f + __expf(-x)); }
__device__ __forceinline__ float tanh_(float x){ float e = __expf(2.f * x); return 1.f - 2.f / (e + 1.f); }

// agent-scope load: L2s are not cross-XCD coherent, so agent loads read at
// the device coherence point (L3/MALL) — NOT the local L2.
__device__ __forceinline__ u64 ald64(const u64* p){
  return __hip_atomic_load(p, __ATOMIC_RELAXED, __HIP_MEMORY_SCOPE_AGENT);
}
__device__ __forceinline__ u32 ald32(const u32* p){
  return __hip_atomic_load(p, __ATOMIC_RELAXED, __HIP_MEMORY_SCOPE_AGENT);
}
// agent-scope store: writes through to the device coherence point. R8
// post-mortem: WORKGROUP-scope stores stop as a dirty line in the local L2,
// which agent-scope pollers (reading L3) cannot see until lazy writeback
// (~10K cycles) — that WAS the enc exchange latency. Producer publishes
// MUST be agent-scope to match the pollers' read point.
__device__ __forceinline__ void ast64(u64* p, u64 v){
  __hip_atomic_store(p, v, __ATOMIC_RELAXED, __HIP_MEMORY_SCOPE_AGENT);
}
__device__ __forceinline__ void ast32(u32* p, u32 v){
  __hip_atomic_store(p, v, __ATOMIC_RELAXED, __HIP_MEMORY_SCOPE_AGENT);
}
__device__ __forceinline__ bf16x8 mk8(u64 a, u64 b){
  union { u64 q[2]; bf16x8 v; } u; u.q[0] = a; u.q[1] = b; return u.v;
}
__device__ __forceinline__ u32 xcc_id(){
  u32 x;
  asm volatile("s_getreg_b32 %0, hwreg(HW_REG_XCC_ID)" : "=s"(x));
  return x & 7u;
}
// MFMA burn while polling (R4: ~neutral on the recurrence, keeps idle CUs
// hot; zero memory traffic)
__device__ __forceinline__ void burn32(f32x4* bacc, bf16x8 junk){
#pragma unroll
  for(int i = 0; i < 8; ++i)
#pragma unroll
    for(int g = 0; g < 4; ++g)
      bacc[g] = __builtin_amdgcn_mfma_f32_16x16x32_bf16(junk, junk, bacc[g], 0, 0, 0);
}
__device__ __forceinline__ void burn_sink(f32x4* bacc){
  asm volatile("" :: "v"(bacc[0][0]), "v"(bacc[1][0]), "v"(bacc[2][0]), "v"(bacc[3][0]));
}

__global__ void fill_kernel(u32* p, u32 v){
  p[blockIdx.x * 256 + threadIdx.x] = v;
}

// fp32 -> bf16 (round-to-nearest-even)
__global__ void cvt_kernel(const float* __restrict__ src, u16* __restrict__ dst, int n){
  const int i = blockIdx.x * 256 + threadIdx.x;
  if(i < n) dst[i] = f2bf(src[i]);
}

// ---------------------------------------------------------------------------
// Encoder, K-SPLIT + FLAG DOORBELL + AGENT-SCOPE PUBLISH: identical to R8
// except the producer's ring data + flag stores are AGENT scope (st64/st32 ->
// ast64/ast32) and the vmcnt fence is dropped (stamp verify backstops any
// flag/data reorder). Theory: consumers' agent-scope polls read L3; the old
// workgroup-scope stores parked data in the local L2 as dirty lines, leaving
// pollers blind until lazy writeback (~10K cy) — the measured D.
// ---------------------------------------------------------------------------
__global__ void __launch_bounds__(256, 1) enc_kernel(
    const int* __restrict__ ids, const u16* __restrict__ emb,
    const u16* __restrict__ Wih, const u16* __restrict__ Whh,
    const float* __restrict__ bih, const float* __restrict__ bhh,
    const u16* __restrict__ W1,  const float* __restrict__ b1,
    u16* hroll, u16* bl, u32* cnt, u32* flags)
{
  extern __shared__ char dynsm[];         // 90 KB reserved (1 block/CU forcing)
  f32x4* pacc = (f32x4*)dynsm;            // [2 buf][2 pair][4 gate][64 lane]
  __shared__ u32 srank;

  const int lane = threadIdx.x & 63;
  const int wvl  = threadIdx.x >> 6;      // 0..3
  const int col  = lane & 15;
  const int quad = lane >> 4;

  const u32 xcd = xcc_id();
  if(xcd >= 4){
    // ---------------- burner: keep the clock domain hot ----------------
    f32x4 bacc[4];
#pragma unroll
    for(int g = 0; g < 4; ++g) bacc[g] = (f32x4){0.f, 0.f, 0.f, 0.f};
    const bf16x8 junk = {0, 0, 0, 0, 0, 0, 0, 0};
    const u32* dp = cnt + 64 + (xcd & 3);
    for(;;){
      if(ald32(dp) != 0u) break;
      burn32(bacc, junk); burn32(bacc, junk);
      burn32(bacc, junk); burn32(bacc, junk);
    }
    burn_sink(bacc);
    return;
  }
  if(threadIdx.x == 0) srank = atomicAdd(&cnt[xcd], 1u);
  __syncthreads();
  const u32 rank = srank;
  const int btile = (int)xcd;
  u32* fbase = flags + (size_t)xcd * (RS * 32);   // [slot][mtile]

  if(rank >= 16){
    if(rank >= 32) return;
    f32x4 bacc[4];
#pragma unroll
    for(int g = 0; g < 4; ++g) bacc[g] = (f32x4){0.f, 0.f, 0.f, 0.f};
    const bf16x8 junk = {0, 0, 0, 0, 0, 0, 0, 0};
    if(wvl != 0){
      // extra worker waves: burn until this XCD's producers finish
      const u32* dp = cnt + 64 + xcd;
      for(;;){
        if(ald32(dp) != 0u) break;
        burn32(bacc, junk); burn32(bacc, junk);
        burn32(bacc, junk); burn32(bacc, junk);
      }
      burn_sink(bacc);
      return;
    }
    // ---------------- blend1 worker: cols [ (rank-16)*16, +16 ) ----------------
    const int n1 = ((int)rank - 16) * 16 + col;
    bf16x8 w1f[16];                       // W1 row n1, register-cached
    const u16* w1p = W1 + (size_t)n1 * NH + quad * 8;
#pragma unroll
    for(int i = 0; i < 16; ++i) w1f[i] = *(const bf16x8*)(w1p + 32 * i);
    const float b1f = b1[n1];
    const int arow = btile * 16 + col;    // h row this lane holds as A-frag

    for(int t = 0; t < NL; ++t){
      const int slot = t & (RS - 1);
      const u32 fwant = (u32)((t >> 4) & 1);
      // flag poll: all 32 mtiles of this slot; burn between misses
      {
        const u32* fp = fbase + slot * 32;
        for(;;){
          const u32 f = ald32(fp + (lane & 31));
          if(__ballot(f == fwant) == ~0ull) break;
          burn32(bacc, junk);
        }
      }
      const u16* ha = hroll + (size_t)slot * NBNH + (size_t)arow * NH + quad * 8;
      const u64 want = fwant ? STM : 0ull;
      u64 hw[32];
      for(;;){                            // verify (flag may race data: retry)
        bool ok = true;
#pragma unroll
        for(int i = 0; i < 16; ++i){
          const u64* p = (const u64*)(ha + 32 * i);
          hw[2 * i]     = ald64(p);
          hw[2 * i + 1] = ald64(p + 1);
          ok = ok && ((hw[2 * i] & STM) == want) && ((hw[2 * i + 1] & STM) == want);
        }
        if(__ballot(ok) == ~0ull) break;
      }
      f32x4 a2 = {0.f, 0.f, 0.f, 0.f};
#pragma unroll
      for(int i = 0; i < 16; ++i)
        a2 = __builtin_amdgcn_mfma_f32_16x16x32_bf16(
               mk8(hw[2 * i] & CLRM, hw[2 * i + 1] & CLRM), w1f[i], a2, 0, 0, 0);
#pragma unroll
      for(int r = 0; r < 4; ++r){
        const int b = btile * 16 + quad * 4 + r;
        bl[((size_t)t * NB + b) * NW + n1] = f2bf(a2[r] + b1f);
      }
    }
    burn_sink(bacc);
    return;
  }

  // ------------------------------ producer ------------------------------
  const int mtile  = (int)rank * 2 + (wvl >> 1);   // 0..31
  const int khalf  = wvl & 1;                      // K-half of the recurrence
  const int pairid = wvl >> 1;                     // LDS pair slot
  const bool lowerw = (khalf == 0);
  const int j  = mtile * 16 + col;                 // hidden index within gate
  const int ab = btile * 16 + col;                 // A-row (batch) this lane loads

  float bias[4];
  const u16* wx[4];
  bf16x8 whr[8][4];                       // Whh fragments, THIS K-half only
#pragma unroll
  for(int g = 0; g < 4; ++g){
    const int row = g * NH + j;           // PyTorch gate order i,f,g,o
    bias[g] = bih[row] + bhh[row];
    wx[g] = Wih + (size_t)row * NE + khalf * 128 + quad * 8;
    const u16* whp = Whh + (size_t)row * NH + khalf * 256 + quad * 8;
#pragma unroll
    for(int i = 0; i < 8; ++i)
      whr[i][g] = *(const bf16x8*)(whp + 32 * i);
  }
  const int* idp = ids + ab * NL;         // ids is [B, L]
  float creg[4] = {0.f, 0.f, 0.f, 0.f};   // cell state (lower wave only live)

  u64 hb[16];                             // h K-half fragment
  f32x4 acc[4];

  // x-part of t=0 (this wave's K-half of NE)
  {
    const u16* xr = emb + (size_t)idp[0] * NE + khalf * 128 + quad * 8;
#pragma unroll
    for(int g = 0; g < 4; ++g) acc[g] = (f32x4){0.f, 0.f, 0.f, 0.f};
#pragma unroll
    for(int k0 = 0; k0 < 128; k0 += 32){
      const bf16x8 af = *(const bf16x8*)(xr + k0);
#pragma unroll
      for(int g = 0; g < 4; ++g)
        acc[g] = __builtin_amdgcn_mfma_f32_16x16x32_bf16(af, *(const bf16x8*)(wx[g] + k0), acc[g], 0, 0, 0);
    }
  }

  for(int t = 0; t < NL; ++t){
    // h-part for step t (hb = K-half of h_{t-1}, polled last iteration)
    if(t > 0){
#pragma unroll
      for(int i = 0; i < 8; ++i){
        const bf16x8 af = mk8(hb[2 * i], hb[2 * i + 1]);
#pragma unroll
        for(int g = 0; g < 4; ++g)
          acc[g] = __builtin_amdgcn_mfma_f32_16x16x32_bf16(af, whr[i][g], acc[g], 0, 0, 0);
      }
    }
    // issue next-step emb loads NOW: latency hides under barrier+epilogue
    bf16x8 xa0, xa1, xa2, xa3;
    const u16* xr = (t + 1 < NL) ? (emb + (size_t)idp[t + 1] * NE + khalf * 128 + quad * 8) : emb;
    xa0 = *(const bf16x8*)(xr);
    xa1 = *(const bf16x8*)(xr + 32);
    xa2 = *(const bf16x8*)(xr + 64);
    xa3 = *(const bf16x8*)(xr + 96);

    const int slot = t & (RS - 1);
    const u32 fphase = (u32)((t >> 4) & 1);

    // K-half merge: upper writes partial acc; one barrier; lower sums + epilogue
    if(!lowerw){
#pragma unroll
      for(int g = 0; g < 4; ++g)
        pacc[(((t & 1) * 2 + pairid) * 4 + g) * 64 + lane] = acc[g];
    }
    __syncthreads();
    if(lowerw){
#pragma unroll
      for(int g = 0; g < 4; ++g){
        const f32x4 pa = pacc[(((t & 1) * 2 + pairid) * 4 + g) * 64 + lane];
        acc[g][0] += pa[0]; acc[g][1] += pa[1]; acc[g][2] += pa[2]; acc[g][3] += pa[3];
      }
      const u64 pst = fphase ? STM : 0ull;
      u16* ho = hroll + (size_t)slot * NBNH;
#pragma unroll
      for(int r = 0; r < 4; ++r){
        const float gi = acc[0][r] + bias[0];
        const float gf = acc[1][r] + bias[1];
        const float gg = acc[2][r] + bias[2];
        const float go = acc[3][r] + bias[3];
        creg[r] = sigm(gf) * creg[r] + sigm(gi) * tanh_(gg);
        const u32 raw  = (u32)f2bf(sigm(go) * tanh_(creg[r]));
        const u32 pair = raw | (((u32)__shfl_xor((int)raw, 1, 64)) << 16);
        const u32 hi   = (u32)__shfl_xor((int)pair, 2, 64);
        if((col & 3) == 0){
          const int row = btile * 16 + quad * 4 + r;
          // R9 CHANGE: agent-scope publish (reaches the pollers' read point)
          ast64((u64*)(ho + (size_t)row * NH + mtile * 16 + col),
                ((u64)pair | ((u64)hi << 32)) | pst);
        }
      }
      // flag doorbell, agent scope (advisory; stamps are the correctness gate)
      if(lane == 0) ast32(fbase + slot * 32 + mtile, fphase);
    }
    if(t + 1 < NL){
      // x-part of t+1 from the pre-issued registers
#pragma unroll
      for(int g = 0; g < 4; ++g) acc[g] = (f32x4){0.f, 0.f, 0.f, 0.f};
#pragma unroll
      for(int g = 0; g < 4; ++g){
        acc[g] = __builtin_amdgcn_mfma_f32_16x16x32_bf16(xa0, *(const bf16x8*)(wx[g]),      acc[g], 0, 0, 0);
        acc[g] = __builtin_amdgcn_mfma_f32_16x16x32_bf16(xa1, *(const bf16x8*)(wx[g] + 32), acc[g], 0, 0, 0);
        acc[g] = __builtin_amdgcn_mfma_f32_16x16x32_bf16(xa2, *(const bf16x8*)(wx[g] + 64), acc[g], 0, 0, 0);
        acc[g] = __builtin_amdgcn_mfma_f32_16x16x32_bf16(xa3, *(const bf16x8*)(wx[g] + 96), acc[g], 0, 0, 0);
      }
      // flag poll: this K-half's 16 mtile flags (64 B / wave / iter)
      {
        const u32* fp = fbase + slot * 32 + khalf * 16;
        for(;;){
          const u32 f = ald32(fp + (lane & 15));
          if(__ballot(f == fphase) == ~0ull) break;
        }
      }
      // data load + stamp verify (retry if flag raced data)
      {
        const u16* ha = hroll + (size_t)slot * NBNH + (size_t)ab * NH + khalf * 256 + quad * 8;
        const u64 want = fphase ? STM : 0ull;
        for(;;){
          bool ok = true;
#pragma unroll
          for(int i = 0; i < 8; ++i){
            const u64* p = (const u64*)(ha + 32 * i);
            hb[2 * i]     = ald64(p);
            hb[2 * i + 1] = ald64(p + 1);
            ok = ok && ((hb[2 * i] & STM) == want) && ((hb[2 * i + 1] & STM) == want);
          }
          if(__ballot(ok) == ~0ull) break;
        }
#pragma unroll
        for(int i = 0; i < 16; ++i) hb[i] &= CLRM;
      }
    }
  }
  // signal burners: this XCD's recurrence is done (agent scope, cross-XCD)
  if(rank == 0 && threadIdx.x == 0) ast32(cnt + 64 + (u32)xcd, 1u);
}

// ---------------------------------------------------------------------------
// Decoder (R8 verbatim): blocks 0..63 = producers (direct agent-scope stores
// into 64 write-once stamped hdX slots; stamp is in-data, self-validating),
// blocks 64..255 = 192 attention workers. c0 = enc h_511 (hroll slot 15).
// ---------------------------------------------------------------------------
__global__ void __launch_bounds__(256, 1) dec_kernel(
    const u16* __restrict__ Whh, const float* __restrict__ bih, const float* __restrict__ bhh,
    const float* __restrict__ W2, const float* __restrict__ b2,
    const float* __restrict__ vt, const float* __restrict__ vtb,
    const u16* __restrict__ bl,  const u16* __restrict__ hroll,
    const float* __restrict__ h0f,
    u16* hdX, float* __restrict__ out)
{
  extern __shared__ char dynsm[];
  f32x4* pacc = (f32x4*)dynsm;            // [2][2][4][64]
  __shared__ __align__(16) float h_f[NH];
  __shared__ __align__(16) float u_lds[NW];
  __shared__ __align__(16) float vt_lds[NW];
  __shared__ float red[8];

  const int tid  = threadIdx.x;
  const int lane = tid & 63;
  const int wvl  = tid >> 6;
  const int col  = lane & 15;
  const int quad = lane >> 4;

  if(blockIdx.x < 64){
    // ------------------------------ producer ------------------------------
    const int btile  = (int)blockIdx.x >> 4;
    const int rank   = (int)blockIdx.x & 15;
    const int mtile  = rank * 2 + (wvl >> 1);
    const int khalf  = wvl & 1;
    const int pairid = wvl >> 1;
    const bool lowerw = (khalf == 0);
    const int j  = mtile * 16 + col;
    const int ab = btile * 16 + col;

    float bias[4];
    bf16x8 whr[8][4];
#pragma unroll
    for(int g = 0; g < 4; ++g){
      const int row = g * NH + j;
      bias[g] = bih[row] + bhh[row];
      const u16* whp = Whh + (size_t)row * NH + khalf * 256 + quad * 8;
#pragma unroll
      for(int i = 0; i < 8; ++i)
        whr[i][g] = *(const bf16x8*)(whp + 32 * i);
    }
    float creg[4] = {0.f, 0.f, 0.f, 0.f};
    if(lowerw){
      // c0 = enc h_511 (hroll slot 15; stamp bits set -> mask)
#pragma unroll
      for(int r = 0; r < 4; ++r){
        const int ci = (btile * 16 + quad * 4 + r) * NH + j;
        creg[r] = bf2f((u16)(hroll[(size_t)15 * NBNH + ci] & 0xBFFFu));
      }
    }
    u64 hb[16];
    f32x4 acc[4];

    // t=0 h-part: h_{-1} = h0 (fp32), this wave's K-half
    {
      const float* hp = h0f + (size_t)ab * NH + khalf * 256 + quad * 8;
#pragma unroll
      for(int g = 0; g < 4; ++g) acc[g] = (f32x4){0.f, 0.f, 0.f, 0.f};
#pragma unroll
      for(int i = 0; i < 8; ++i){
        const f32x4 a0 = *(const f32x4*)(hp + 32 * i);
        const f32x4 a1 = *(const f32x4*)(hp + 32 * i + 4);
        bf16x8 af;
#pragma unroll
        for(int q = 0; q < 4; ++q){ af[q] = (short)f2bf(a0[q]); af[q + 4] = (short)f2bf(a1[q]); }
#pragma unroll
        for(int g = 0; g < 4; ++g)
          acc[g] = __builtin_amdgcn_mfma_f32_16x16x32_bf16(af, whr[i][g], acc[g], 0, 0, 0);
      }
    }

    for(int t = 0; t < NT; ++t){
      if(t > 0){
#pragma unroll
        for(int g = 0; g < 4; ++g) acc[g] = (f32x4){0.f, 0.f, 0.f, 0.f};
#pragma unroll
        for(int i = 0; i < 8; ++i){
          const bf16x8 af = mk8(hb[2 * i], hb[2 * i + 1]);
#pragma unroll
          for(int g = 0; g < 4; ++g)
            acc[g] = __builtin_amdgcn_mfma_f32_16x16x32_bf16(af, whr[i][g], acc[g], 0, 0, 0);
        }
      }
      if(!lowerw){
#pragma unroll
        for(int g = 0; g < 4; ++g)
          pacc[(((t & 1) * 2 + pairid) * 4 + g) * 64 + lane] = acc[g];
      }
      __syncthreads();
      if(lowerw){
#pragma unroll
        for(int g = 0; g < 4; ++g){
          const f32x4 pa = pacc[(((t & 1) * 2 + pairid) * 4 + g) * 64 + lane];
          acc[g][0] += pa[0]; acc[g][1] += pa[1]; acc[g][2] += pa[2]; acc[g][3] += pa[3];
        }
        // epilogue: h_t stamped -> write-once slot t (agent scope, direct)
        u16* hn = hdX + (size_t)t * NBNH;
#pragma unroll
        for(int r = 0; r < 4; ++r){
          const float gi = acc[0][r] + bias[0];
          const float gf = acc[1][r] + bias[1];
          const float gg = acc[2][r] + bias[2];
          const float go = acc[3][r] + bias[3];
          creg[r] = sigm(gf) * creg[r] + sigm(gi) * tanh_(gg);
          const u32 stv  = (u32)f2bf(sigm(go) * tanh_(creg[r])) | 0x4000u;
          const u32 pair = stv | (((u32)__shfl_xor((int)stv, 1, 64)) << 16);
          const u32 hi   = (u32)__shfl_xor((int)pair, 2, 64);
          if((col & 3) == 0){
            const int row = btile * 16 + quad * 4 + r;
            ast64((u64*)(hn + (size_t)row * NH + mtile * 16 + col),
                  (u64)pair | ((u64)hi << 32));
          }
        }
      }
      if(t + 1 < NT){
        // poll slot t directly (write-once, stamp in data, no flags)
        const u16* ha = hdX + (size_t)t * NBNH + (size_t)ab * NH + khalf * 256 + quad * 8;
        for(;;){
          bool ok = true;
#pragma unroll
          for(int i = 0; i < 8; ++i){
            const u64* p = (const u64*)(ha + 32 * i);
            hb[2 * i]     = ald64(p);
            hb[2 * i + 1] = ald64(p + 1);
            ok = ok && ((hb[2 * i] & STM) == STM) && ((hb[2 * i + 1] & STM) == STM);
          }
          if(__ballot(ok) == ~0ull) break;
        }
#pragma unroll
        for(int i = 0; i < 16; ++i) hb[i] &= CLRM;
      }
    }
    return;
  }

  // ------------------------- attention worker path -------------------------
  const int wid = (int)blockIdx.x - 64;   // 0..191

  vt_lds[tid] = vt[tid];
  const float vtbf = vtb[0];
  __syncthreads();

  f32x4 bacc[4];
#pragma unroll
  for(int g = 0; g < 4; ++g) bacc[g] = (f32x4){0.f, 0.f, 0.f, 0.f};
  const bf16x8 junk = {0, 0, 0, 0, 0, 0, 0, 0};

  for(int tk = wid; tk < NT * NB; tk += 192){
    const int t = tk >> 6;
    const int b = tk & 63;

    // poll slot t row b (stamped bf16), stage -> fp32 LDS (burn-throttled)
    {
      const u32* hp = (const u32*)(hdX + (size_t)t * NBNH + (size_t)b * NH);
      u32 v;
      for(;;){
        v = ald32(hp + tid);
        burn32(bacc, junk);
        const int ok = ((v & 0x40004000u) == 0x40004000u) ? 1 : 0;
        if(__syncthreads_and(ok)) break;
      }
      h_f[2 * tid]     = bf2f((u16)(v & 0xBFFFu));
      h_f[2 * tid + 1] = bf2f((u16)((v >> 16) & 0xBFFFu));
    }
    __syncthreads();

    // u[n] = b2[n] + h . W2[n,:]   (h broadcast from LDS, f32x4 loads)
    {
      const float* w2r = W2 + (size_t)tid * NH;
      float s = b2[tid];
#pragma unroll 4
      for(int k = 0; k < NH; k += 4){
        const f32x4 hv = *(const f32x4*)(&h_f[k]);
        const f32x4 wv = *(const f32x4*)(w2r + k);
        s += hv[0] * wv[0] + hv[1] * wv[1] + hv[2] * wv[2] + hv[3] * wv[3];
      }
      u_lds[tid] = s;
    }
    __syncthreads();

    // scores for l = tid and l = tid+256 (bf16x8 row loads)
    float a0, a1;
#pragma unroll
    for(int e = 0; e < 2; ++e){
      const int l = tid + e * 256;
      const u16* br = bl + (size_t)(l * NB + b) * NW;
      float p = 0.f;
#pragma unroll 2
      for(int w0 = 0; w0 < NW; w0 += 8){
        const bf16x8 bv = *(const bf16x8*)(br + w0);
#pragma unroll
        for(int q = 0; q < 8; ++q)
          p += vt_lds[w0 + q] * tanh_(bf2f((u16)bv[q]) + u_lds[w0 + q]);
      }
      if(e == 0) a0 = p + vtbf; else a1 = p + vtbf;
    }

    // log-softmax over L = 512 (2 values per thread, block-wide reduction)
    float mx = fmaxf(a0, a1);
#pragma unroll
    for(int off = 32; off > 0; off >>= 1) mx = fmaxf(mx, __shfl_xor(mx, off, 64));
    if(lane == 0) red[wvl] = mx;
    __syncthreads();
    mx = fmaxf(fmaxf(red[0], red[1]), fmaxf(red[2], red[3]));
    float es = __expf(a0 - mx) + __expf(a1 - mx);
#pragma unroll
    for(int off = 32; off > 0; off >>= 1) es += __shfl_xor(es, off, 64);
    if(lane == 0) red[4 + wvl] = es;
    __syncthreads();
    const float lse = mx + logf(red[4] + red[5] + red[6] + red[7]);
    out[((size_t)tid * NB + b) * NT + t]         = a0 - lse;
    out[((size_t)(tid + 256) * NB + b) * NT + t] = a1 - lse;
    __syncthreads();
  }
  burn_sink(bacc);
}

// ---------------------------------------------------------------------------
extern "C" void kernel_launch(void* const* d_in, const int* in_sizes, int n_in,
                              void* d_out, int out_size, void* d_ws, size_t ws_size,
                              hipStream_t stream)
{
  (void)in_sizes; (void)n_in; (void)out_size; (void)ws_size;
  const int*   ids  = (const int*)d_in[0];
  const float* emb  = (const float*)d_in[1];
  const float* eWih = (const float*)d_in[2];
  const float* eWhh = (const float*)d_in[3];
  const float* ebih = (const float*)d_in[4];
  const float* ebhh = (const float*)d_in[5];
  /* d_in[6] = dec_Wih: unused (decoder input is identically zero) */
  const float* dWhh = (const float*)d_in[7];
  const float* dbih = (const float*)d_in[8];
  const float* dbhh = (const float*)d_in[9];
  const float* W1   = (const float*)d_in[10];
  const float* b1   = (const float*)d_in[11];
  const float* W2   = (const float*)d_in[12];
  const float* b2   = (const float*)d_in[13];
  const float* vt   = (const float*)d_in[14];
  const float* vtb  = (const float*)d_in[15];
  const float* h0   = (const float*)d_in[16];

  // workspace ~28.5 MB. X = bf16 emb during enc, then dec's 64 write-once h
  // slots (hdX; stale emb bf16 has bit14 clear for |v|<2 -> stamps valid
  // without pre-zeroing). hroll = enc's 16-deep h ring (slot 15 = h_511
  // feeds dec c0). flags = enc doorbells. cnt[64..67] = per-XCD enc-done.
  char* ws = (char*)d_ws;
  u16* bl     = (u16*)ws; ws += (size_t)NL * NB * NW * 2;    // blend1 bf16  16.78 MB
  u16* hroll  = (u16*)ws; ws += (size_t)RS * NBNH * 2;       // h ring       1.05 MB
  u16* X      = (u16*)ws; ws += (size_t)10000 * NE * 2;      // emb_b / hdec 5.12 MB
  u16* eWih_b = (u16*)ws; ws += (size_t)4 * NH * NE * 2;     // 1.05 MB
  u16* eWhh_b = (u16*)ws; ws += (size_t)4 * NH * NH * 2;     // 2.10 MB
  u16* dWhh_b = (u16*)ws; ws += (size_t)4 * NH * NH * 2;     // 2.10 MB
  u16* W1_b   = (u16*)ws; ws += (size_t)NW * NH * 2;         // 0.26 MB
  u32* cnt    = (u32*)ws; ws += 1024;                        // rank/done counters
  u32* flags  = (u32*)ws; ws += (size_t)4 * RS * 32 * 4;     // doorbells 8 KB

  // ring + flags pre-filled with phase-1 pattern; counters zeroed
  hipLaunchKernelGGL(fill_kernel, dim3((RS * NBNH / 2) / 256), dim3(256), 0, stream,
                     (u32*)hroll, 0x40004000u);
  hipLaunchKernelGGL(fill_kernel, dim3(8), dim3(256), 0, stream, flags, 1u);
  hipLaunchKernelGGL(fill_kernel, dim3(1), dim3(256), 0, stream, cnt, 0u);
  hipLaunchKernelGGL(cvt_kernel, dim3(10000), dim3(256), 0, stream, emb,  X,      10000 * NE);
  hipLaunchKernelGGL(cvt_kernel, dim3(2048),  dim3(256), 0, stream, eWih, eWih_b, 4 * NH * NE);
  hipLaunchKernelGGL(cvt_kernel, dim3(4096),  dim3(256), 0, stream, eWhh, eWhh_b, 4 * NH * NH);
  hipLaunchKernelGGL(cvt_kernel, dim3(4096),  dim3(256), 0, stream, dWhh, dWhh_b, 4 * NH * NH);
  hipLaunchKernelGGL(cvt_kernel, dim3(512),   dim3(256), 0, stream, W1,   W1_b,   NW * NH);

  // 90 KB dynamic LDS -> 1 block/CU -> 256-block grid is a bijection onto
  // CUs (enc: XCD pigeonhole; dec: producer/worker isolation per CU)
  hipLaunchKernelGGL(enc_kernel, dim3(256), dim3(256), 92160, stream,
                     ids, X, eWih_b, eWhh_b, ebih, ebhh, W1_b, b1, hroll, bl, cnt, flags);
  hipLaunchKernelGGL(dec_kernel, dim3(256), dim3(256), 92160, stream,
                     dWhh_b, dbih, dbhh, W2, b2, vt, vtb, bl, hroll, h0, X,
                     (float*)d_out);
}

// Round 13
// 4200.674 us; speedup vs baseline: 1.0326x; 1.0326x over previous
//
#include <hip/hip_runtime.h>

#define NB 64      // batch
#define NL 512     // seq len
#define NT 64      // answer len
#define NH 512     // hidden
#define NE 256     // emb dim
#define NW 256     // attention weight dim
#define NBNH (NB * NH)
#define RS 16      // h-ring depth (slots); phase stamp = (t>>4)&1

typedef __attribute__((ext_vector_type(8))) short bf16x8;
typedef __attribute__((ext_vector_type(4))) float f32x4;
typedef unsigned short u16;
typedef unsigned int u32;
typedef unsigned long long u64;

#define STM 0x4000400040004000ull   // bit14 of each u16 (never set in bf16 of |v|<2)
#define CLRM 0xBFFFBFFFBFFFBFFFull

__device__ __forceinline__ float bf2f(u16 v){
  union { u32 u; float f; } x; x.u = ((u32)v) << 16; return x.f;
}
__device__ __forceinline__ u16 f2bf(float f){
  union { float f; u32 u; } x; x.f = f;
  return (u16)((x.u + 0x7FFFu + ((x.u >> 16) & 1u)) >> 16);
}
__device__ __forceinline__ float sigm(float x){ return 1.f / (1.f + __expf(-x)); }
__device__ __forceinline__ float tanh_(float x){ float e = __expf(2.f * x); return 1.f - 2.f / (e + 1.f); }

// agent-scope load: bypasses L1, reads the local-XCD L2 (R9 FETCH evidence:
// these polls are L2 hits when the data is published workgroup-scope, and
// become L3 fetches when publishes overshoot to the coherence point)
__device__ __forceinline__ u64 ald64(const u64* p){
  return __hip_atomic_load(p, __ATOMIC_RELAXED, __HIP_MEMORY_SCOPE_AGENT);
}
__device__ __forceinline__ u32 ald32(const u32* p){
  return __hip_atomic_load(p, __ATOMIC_RELAXED, __HIP_MEMORY_SCOPE_AGENT);
}
// agent-scope store: pushes to the device coherence point (cross-XCD safe;
// used ONLY by dec producers whose consumers live on other XCDs)
__device__ __forceinline__ void ast64(u64* p, u64 v){
  __hip_atomic_store(p, v, __ATOMIC_RELAXED, __HIP_MEMORY_SCOPE_AGENT);
}
__device__ __forceinline__ void ast32(u32* p, u32 v){
  __hip_atomic_store(p, v, __ATOMIC_RELAXED, __HIP_MEMORY_SCOPE_AGENT);
}
// R12: ATOMIC-EXCHANGE publish — executes AT the local L2 (atomics bypass the
// L1/write-combine store path entirely), workgroup scope keeps it in the
// local XCD's L2 where the ald pollers read. Tests the one untested
// producer-side mechanism: vmcnt retires at store-ACCEPT (WC), not L2-visible
// (R7 fence null); partial-line masked stores are the classic lazy-WC drain.
__device__ __forceinline__ void axch64(u64* p, u64 v){
  (void)__hip_atomic_exchange(p, v, __ATOMIC_RELAXED, __HIP_MEMORY_SCOPE_WORKGROUP);
}
__device__ __forceinline__ void axch32(u32* p, u32 v){
  (void)__hip_atomic_exchange(p, v, __ATOMIC_RELAXED, __HIP_MEMORY_SCOPE_WORKGROUP);
}
__device__ __forceinline__ bf16x8 mk8(u64 a, u64 b){
  union { u64 q[2]; bf16x8 v; } u; u.q[0] = a; u.q[1] = b; return u.v;
}
__device__ __forceinline__ u32 xcc_id(){
  u32 x;
  asm volatile("s_getreg_b32 %0, hwreg(HW_REG_XCC_ID)" : "=s"(x));
  return x & 7u;
}
// MFMA burn while polling (keeps idle CUs hot; zero memory traffic)
__device__ __forceinline__ void burn32(f32x4* bacc, bf16x8 junk){
#pragma unroll
  for(int i = 0; i < 8; ++i)
#pragma unroll
    for(int g = 0; g < 4; ++g)
      bacc[g] = __builtin_amdgcn_mfma_f32_16x16x32_bf16(junk, junk, bacc[g], 0, 0, 0);
}
__device__ __forceinline__ void burn_sink(f32x4* bacc){
  asm volatile("" :: "v"(bacc[0][0]), "v"(bacc[1][0]), "v"(bacc[2][0]), "v"(bacc[3][0]));
}

__global__ void fill_kernel(u32* p, u32 v){
  p[blockIdx.x * 256 + threadIdx.x] = v;
}

// fp32 -> bf16 (round-to-nearest-even)
__global__ void cvt_kernel(const float* __restrict__ src, u16* __restrict__ dst, int n){
  const int i = blockIdx.x * 256 + threadIdx.x;
  if(i < n) dst[i] = f2bf(src[i]);
}

// ---------------------------------------------------------------------------
// Encoder: R8 structure verbatim (flag doorbell, burn-on-idle, ald polls)
// with ONE change — producer publishes (ring data + flag) via atomicExch
// (executes at the local L2, skipping the L1/WC store path).
// ---------------------------------------------------------------------------
__global__ void __launch_bounds__(256, 1) enc_kernel(
    const int* __restrict__ ids, const u16* __restrict__ emb,
    const u16* __restrict__ Wih, const u16* __restrict__ Whh,
    const float* __restrict__ bih, const float* __restrict__ bhh,
    const u16* __restrict__ W1,  const float* __restrict__ b1,
    u16* hroll, u16* bl, u32* cnt, u32* flags)
{
  extern __shared__ char dynsm[];         // 90 KB reserved (1 block/CU forcing)
  f32x4* pacc = (f32x4*)dynsm;            // [2 buf][2 pair][4 gate][64 lane]
  __shared__ u32 srank;

  const int lane = threadIdx.x & 63;
  const int wvl  = threadIdx.x >> 6;      // 0..3
  const int col  = lane & 15;
  const int quad = lane >> 4;

  const u32 xcd = xcc_id();
  if(xcd >= 4){
    // ---------------- burner: keep the clock domain hot ----------------
    f32x4 bacc[4];
#pragma unroll
    for(int g = 0; g < 4; ++g) bacc[g] = (f32x4){0.f, 0.f, 0.f, 0.f};
    const bf16x8 junk = {0, 0, 0, 0, 0, 0, 0, 0};
    const u32* dp = cnt + 64 + (xcd & 3);
    for(;;){
      if(ald32(dp) != 0u) break;
      burn32(bacc, junk); burn32(bacc, junk);
      burn32(bacc, junk); burn32(bacc, junk);
    }
    burn_sink(bacc);
    return;
  }
  if(threadIdx.x == 0) srank = atomicAdd(&cnt[xcd], 1u);
  __syncthreads();
  const u32 rank = srank;
  const int btile = (int)xcd;
  u32* fbase = flags + (size_t)xcd * (RS * 32);   // [slot][mtile]

  if(rank >= 16){
    if(rank >= 32) return;
    f32x4 bacc[4];
#pragma unroll
    for(int g = 0; g < 4; ++g) bacc[g] = (f32x4){0.f, 0.f, 0.f, 0.f};
    const bf16x8 junk = {0, 0, 0, 0, 0, 0, 0, 0};
    if(wvl != 0){
      // extra worker waves: burn until this XCD's producers finish
      const u32* dp = cnt + 64 + xcd;
      for(;;){
        if(ald32(dp) != 0u) break;
        burn32(bacc, junk); burn32(bacc, junk);
        burn32(bacc, junk); burn32(bacc, junk);
      }
      burn_sink(bacc);
      return;
    }
    // ---------------- blend1 worker: cols [ (rank-16)*16, +16 ) ----------------
    const int n1 = ((int)rank - 16) * 16 + col;
    bf16x8 w1f[16];                       // W1 row n1, register-cached
    const u16* w1p = W1 + (size_t)n1 * NH + quad * 8;
#pragma unroll
    for(int i = 0; i < 16; ++i) w1f[i] = *(const bf16x8*)(w1p + 32 * i);
    const float b1f = b1[n1];
    const int arow = btile * 16 + col;    // h row this lane holds as A-frag

    for(int t = 0; t < NL; ++t){
      const int slot = t & (RS - 1);
      const u32 fwant = (u32)((t >> 4) & 1);
      // flag poll: all 32 mtiles of this slot; burn between misses
      {
        const u32* fp = fbase + slot * 32;
        for(;;){
          const u32 f = ald32(fp + (lane & 31));
          if(__ballot(f == fwant) == ~0ull) break;
          burn32(bacc, junk);
        }
      }
      const u16* ha = hroll + (size_t)slot * NBNH + (size_t)arow * NH + quad * 8;
      const u64 want = fwant ? STM : 0ull;
      u64 hw[32];
      for(;;){                            // verify (flag may race data: retry)
        bool ok = true;
#pragma unroll
        for(int i = 0; i < 16; ++i){
          const u64* p = (const u64*)(ha + 32 * i);
          hw[2 * i]     = ald64(p);
          hw[2 * i + 1] = ald64(p + 1);
          ok = ok && ((hw[2 * i] & STM) == want) && ((hw[2 * i + 1] & STM) == want);
        }
        if(__ballot(ok) == ~0ull) break;
      }
      f32x4 a2 = {0.f, 0.f, 0.f, 0.f};
#pragma unroll
      for(int i = 0; i < 16; ++i)
        a2 = __builtin_amdgcn_mfma_f32_16x16x32_bf16(
               mk8(hw[2 * i] & CLRM, hw[2 * i + 1] & CLRM), w1f[i], a2, 0, 0, 0);
#pragma unroll
      for(int r = 0; r < 4; ++r){
        const int b = btile * 16 + quad * 4 + r;
        bl[((size_t)t * NB + b) * NW + n1] = f2bf(a2[r] + b1f);
      }
    }
    burn_sink(bacc);
    return;
  }

  // ------------------------------ producer ------------------------------
  const int mtile  = (int)rank * 2 + (wvl >> 1);   // 0..31
  const int khalf  = wvl & 1;                      // K-half of the recurrence
  const int pairid = wvl >> 1;                     // LDS pair slot
  const bool lowerw = (khalf == 0);
  const int j  = mtile * 16 + col;                 // hidden index within gate
  const int ab = btile * 16 + col;                 // A-row (batch) this lane loads

  float bias[4];
  const u16* wx[4];
  bf16x8 whr[8][4];                       // Whh fragments, THIS K-half only
#pragma unroll
  for(int g = 0; g < 4; ++g){
    const int row = g * NH + j;           // PyTorch gate order i,f,g,o
    bias[g] = bih[row] + bhh[row];
    wx[g] = Wih + (size_t)row * NE + khalf * 128 + quad * 8;
    const u16* whp = Whh + (size_t)row * NH + khalf * 256 + quad * 8;
#pragma unroll
    for(int i = 0; i < 8; ++i)
      whr[i][g] = *(const bf16x8*)(whp + 32 * i);
  }
  const int* idp = ids + ab * NL;         // ids is [B, L]
  float creg[4] = {0.f, 0.f, 0.f, 0.f};   // cell state (lower wave only live)

  u64 hb[16];                             // h K-half fragment
  f32x4 acc[4];

  // x-part of t=0 (this wave's K-half of NE)
  {
    const u16* xr = emb + (size_t)idp[0] * NE + khalf * 128 + quad * 8;
#pragma unroll
    for(int g = 0; g < 4; ++g) acc[g] = (f32x4){0.f, 0.f, 0.f, 0.f};
#pragma unroll
    for(int k0 = 0; k0 < 128; k0 += 32){
      const bf16x8 af = *(const bf16x8*)(xr + k0);
#pragma unroll
      for(int g = 0; g < 4; ++g)
        acc[g] = __builtin_amdgcn_mfma_f32_16x16x32_bf16(af, *(const bf16x8*)(wx[g] + k0), acc[g], 0, 0, 0);
    }
  }

  for(int t = 0; t < NL; ++t){
    // h-part for step t (hb = K-half of h_{t-1}, polled last iteration)
    if(t > 0){
#pragma unroll
      for(int i = 0; i < 8; ++i){
        const bf16x8 af = mk8(hb[2 * i], hb[2 * i + 1]);
#pragma unroll
        for(int g = 0; g < 4; ++g)
          acc[g] = __builtin_amdgcn_mfma_f32_16x16x32_bf16(af, whr[i][g], acc[g], 0, 0, 0);
      }
    }
    // issue next-step emb loads NOW: latency hides under barrier+epilogue
    bf16x8 xa0, xa1, xa2, xa3;
    const u16* xr = (t + 1 < NL) ? (emb + (size_t)idp[t + 1] * NE + khalf * 128 + quad * 8) : emb;
    xa0 = *(const bf16x8*)(xr);
    xa1 = *(const bf16x8*)(xr + 32);
    xa2 = *(const bf16x8*)(xr + 64);
    xa3 = *(const bf16x8*)(xr + 96);

    const int slot = t & (RS - 1);
    const u32 fphase = (u32)((t >> 4) & 1);

    // K-half merge: upper writes partial acc; one barrier; lower sums + epilogue
    if(!lowerw){
#pragma unroll
      for(int g = 0; g < 4; ++g)
        pacc[(((t & 1) * 2 + pairid) * 4 + g) * 64 + lane] = acc[g];
    }
    __syncthreads();
    if(lowerw){
#pragma unroll
      for(int g = 0; g < 4; ++g){
        const f32x4 pa = pacc[(((t & 1) * 2 + pairid) * 4 + g) * 64 + lane];
        acc[g][0] += pa[0]; acc[g][1] += pa[1]; acc[g][2] += pa[2]; acc[g][3] += pa[3];
      }
      const u64 pst = fphase ? STM : 0ull;
      u16* ho = hroll + (size_t)slot * NBNH;
#pragma unroll
      for(int r = 0; r < 4; ++r){
        const float gi = acc[0][r] + bias[0];
        const float gf = acc[1][r] + bias[1];
        const float gg = acc[2][r] + bias[2];
        const float go = acc[3][r] + bias[3];
        creg[r] = sigm(gf) * creg[r] + sigm(gi) * tanh_(gg);
        const u32 raw  = (u32)f2bf(sigm(go) * tanh_(creg[r]));
        const u32 pair = raw | (((u32)__shfl_xor((int)raw, 1, 64)) << 16);
        const u32 hi   = (u32)__shfl_xor((int)pair, 2, 64);
        if((col & 3) == 0){
          const int row = btile * 16 + quad * 4 + r;
          // R12 CHANGE: atomic publish — lands in the local L2 immediately
          axch64((u64*)(ho + (size_t)row * NH + mtile * 16 + col),
                 ((u64)pair | ((u64)hi << 32)) | pst);
        }
      }
      // flag doorbell via atomic (advisory; data stamps = correctness gate)
      if(lane == 0) axch32(fbase + slot * 32 + mtile, fphase);
    }
    if(t + 1 < NL){
      // x-part of t+1 from the pre-issued registers
#pragma unroll
      for(int g = 0; g < 4; ++g) acc[g] = (f32x4){0.f, 0.f, 0.f, 0.f};
#pragma unroll
      for(int g = 0; g < 4; ++g){
        acc[g] = __builtin_amdgcn_mfma_f32_16x16x32_bf16(xa0, *(const bf16x8*)(wx[g]),      acc[g], 0, 0, 0);
        acc[g] = __builtin_amdgcn_mfma_f32_16x16x32_bf16(xa1, *(const bf16x8*)(wx[g] + 32), acc[g], 0, 0, 0);
        acc[g] = __builtin_amdgcn_mfma_f32_16x16x32_bf16(xa2, *(const bf16x8*)(wx[g] + 64), acc[g], 0, 0, 0);
        acc[g] = __builtin_amdgcn_mfma_f32_16x16x32_bf16(xa3, *(const bf16x8*)(wx[g] + 96), acc[g], 0, 0, 0);
      }
      // flag poll: this K-half's 16 mtile flags (64 B / wave / iter)
      {
        const u32* fp = fbase + slot * 32 + khalf * 16;
        for(;;){
          const u32 f = ald32(fp + (lane & 15));
          if(__ballot(f == fphase) == ~0ull) break;
        }
      }
      // data load + stamp verify (retry if flag raced data)
      {
        const u16* ha = hroll + (size_t)slot * NBNH + (size_t)ab * NH + khalf * 256 + quad * 8;
        const u64 want = fphase ? STM : 0ull;
        for(;;){
          bool ok = true;
#pragma unroll
          for(int i = 0; i < 8; ++i){
            const u64* p = (const u64*)(ha + 32 * i);
            hb[2 * i]     = ald64(p);
            hb[2 * i + 1] = ald64(p + 1);
            ok = ok && ((hb[2 * i] & STM) == want) && ((hb[2 * i + 1] & STM) == want);
          }
          if(__ballot(ok) == ~0ull) break;
        }
#pragma unroll
        for(int i = 0; i < 16; ++i) hb[i] &= CLRM;
      }
    }
  }
  // signal burners: this XCD's recurrence is done (agent scope, cross-XCD)
  if(rank == 0 && threadIdx.x == 0) ast32(cnt + 64 + (u32)xcd, 1u);
}

// ---------------------------------------------------------------------------
// Decoder (R8 verbatim): blocks 0..63 = producers (direct agent-scope stores
// into 64 write-once stamped hdX slots; stamp is in-data, self-validating),
// blocks 64..255 = 192 attention workers. c0 = enc h_511 (hroll slot 15).
// ---------------------------------------------------------------------------
__global__ void __launch_bounds__(256, 1) dec_kernel(
    const u16* __restrict__ Whh, const float* __restrict__ bih, const float* __restrict__ bhh,
    const float* __restrict__ W2, const float* __restrict__ b2,
    const float* __restrict__ vt, const float* __restrict__ vtb,
    const u16* __restrict__ bl,  const u16* __restrict__ hroll,
    const float* __restrict__ h0f,
    u16* hdX, float* __restrict__ out)
{
  extern __shared__ char dynsm[];
  f32x4* pacc = (f32x4*)dynsm;            // [2][2][4][64]
  __shared__ __align__(16) float h_f[NH];
  __shared__ __align__(16) float u_lds[NW];
  __shared__ __align__(16) float vt_lds[NW];
  __shared__ float red[8];

  const int tid  = threadIdx.x;
  const int lane = tid & 63;
  const int wvl  = tid >> 6;
  const int col  = lane & 15;
  const int quad = lane >> 4;

  if(blockIdx.x < 64){
    // ------------------------------ producer ------------------------------
    const int btile  = (int)blockIdx.x >> 4;
    const int rank   = (int)blockIdx.x & 15;
    const int mtile  = rank * 2 + (wvl >> 1);
    const int khalf  = wvl & 1;
    const int pairid = wvl >> 1;
    const bool lowerw = (khalf == 0);
    const int j  = mtile * 16 + col;
    const int ab = btile * 16 + col;

    float bias[4];
    bf16x8 whr[8][4];
#pragma unroll
    for(int g = 0; g < 4; ++g){
      const int row = g * NH + j;
      bias[g] = bih[row] + bhh[row];
      const u16* whp = Whh + (size_t)row * NH + khalf * 256 + quad * 8;
#pragma unroll
      for(int i = 0; i < 8; ++i)
        whr[i][g] = *(const bf16x8*)(whp + 32 * i);
    }
    float creg[4] = {0.f, 0.f, 0.f, 0.f};
    if(lowerw){
      // c0 = enc h_511 (hroll slot 15; stamp bits set -> mask)
#pragma unroll
      for(int r = 0; r < 4; ++r){
        const int ci = (btile * 16 + quad * 4 + r) * NH + j;
        creg[r] = bf2f((u16)(hroll[(size_t)15 * NBNH + ci] & 0xBFFFu));
      }
    }
    u64 hb[16];
    f32x4 acc[4];

    // t=0 h-part: h_{-1} = h0 (fp32), this wave's K-half
    {
      const float* hp = h0f + (size_t)ab * NH + khalf * 256 + quad * 8;
#pragma unroll
      for(int g = 0; g < 4; ++g) acc[g] = (f32x4){0.f, 0.f, 0.f, 0.f};
#pragma unroll
      for(int i = 0; i < 8; ++i){
        const f32x4 a0 = *(const f32x4*)(hp + 32 * i);
        const f32x4 a1 = *(const f32x4*)(hp + 32 * i + 4);
        bf16x8 af;
#pragma unroll
        for(int q = 0; q < 4; ++q){ af[q] = (short)f2bf(a0[q]); af[q + 4] = (short)f2bf(a1[q]); }
#pragma unroll
        for(int g = 0; g < 4; ++g)
          acc[g] = __builtin_amdgcn_mfma_f32_16x16x32_bf16(af, whr[i][g], acc[g], 0, 0, 0);
      }
    }

    for(int t = 0; t < NT; ++t){
      if(t > 0){
#pragma unroll
        for(int g = 0; g < 4; ++g) acc[g] = (f32x4){0.f, 0.f, 0.f, 0.f};
#pragma unroll
        for(int i = 0; i < 8; ++i){
          const bf16x8 af = mk8(hb[2 * i], hb[2 * i + 1]);
#pragma unroll
          for(int g = 0; g < 4; ++g)
            acc[g] = __builtin_amdgcn_mfma_f32_16x16x32_bf16(af, whr[i][g], acc[g], 0, 0, 0);
        }
      }
      if(!lowerw){
#pragma unroll
        for(int g = 0; g < 4; ++g)
          pacc[(((t & 1) * 2 + pairid) * 4 + g) * 64 + lane] = acc[g];
      }
      __syncthreads();
      if(lowerw){
#pragma unroll
        for(int g = 0; g < 4; ++g){
          const f32x4 pa = pacc[(((t & 1) * 2 + pairid) * 4 + g) * 64 + lane];
          acc[g][0] += pa[0]; acc[g][1] += pa[1]; acc[g][2] += pa[2]; acc[g][3] += pa[3];
        }
        // epilogue: h_t stamped -> write-once slot t (agent scope, direct)
        u16* hn = hdX + (size_t)t * NBNH;
#pragma unroll
        for(int r = 0; r < 4; ++r){
          const float gi = acc[0][r] + bias[0];
          const float gf = acc[1][r] + bias[1];
          const float gg = acc[2][r] + bias[2];
          const float go = acc[3][r] + bias[3];
          creg[r] = sigm(gf) * creg[r] + sigm(gi) * tanh_(gg);
          const u32 stv  = (u32)f2bf(sigm(go) * tanh_(creg[r])) | 0x4000u;
          const u32 pair = stv | (((u32)__shfl_xor((int)stv, 1, 64)) << 16);
          const u32 hi   = (u32)__shfl_xor((int)pair, 2, 64);
          if((col & 3) == 0){
            const int row = btile * 16 + quad * 4 + r;
            ast64((u64*)(hn + (size_t)row * NH + mtile * 16 + col),
                  (u64)pair | ((u64)hi << 32));
          }
        }
      }
      if(t + 1 < NT){
        // poll slot t directly (write-once, stamp in data, no flags)
        const u16* ha = hdX + (size_t)t * NBNH + (size_t)ab * NH + khalf * 256 + quad * 8;
        for(;;){
          bool ok = true;
#pragma unroll
          for(int i = 0; i < 8; ++i){
            const u64* p = (const u64*)(ha + 32 * i);
            hb[2 * i]     = ald64(p);
            hb[2 * i + 1] = ald64(p + 1);
            ok = ok && ((hb[2 * i] & STM) == STM) && ((hb[2 * i + 1] & STM) == STM);
          }
          if(__ballot(ok) == ~0ull) break;
        }
#pragma unroll
        for(int i = 0; i < 16; ++i) hb[i] &= CLRM;
      }
    }
    return;
  }

  // ------------------------- attention worker path -------------------------
  const int wid = (int)blockIdx.x - 64;   // 0..191

  vt_lds[tid] = vt[tid];
  const float vtbf = vtb[0];
  __syncthreads();

  f32x4 bacc[4];
#pragma unroll
  for(int g = 0; g < 4; ++g) bacc[g] = (f32x4){0.f, 0.f, 0.f, 0.f};
  const bf16x8 junk = {0, 0, 0, 0, 0, 0, 0, 0};

  for(int tk = wid; tk < NT * NB; tk += 192){
    const int t = tk >> 6;
    const int b = tk & 63;

    // poll slot t row b (stamped bf16), stage -> fp32 LDS (burn-throttled)
    {
      const u32* hp = (const u32*)(hdX + (size_t)t * NBNH + (size_t)b * NH);
      u32 v;
      for(;;){
        v = ald32(hp + tid);
        burn32(bacc, junk);
        const int ok = ((v & 0x40004000u) == 0x40004000u) ? 1 : 0;
        if(__syncthreads_and(ok)) break;
      }
      h_f[2 * tid]     = bf2f((u16)(v & 0xBFFFu));
      h_f[2 * tid + 1] = bf2f((u16)((v >> 16) & 0xBFFFu));
    }
    __syncthreads();

    // u[n] = b2[n] + h . W2[n,:]   (h broadcast from LDS, f32x4 loads)
    {
      const float* w2r = W2 + (size_t)tid * NH;
      float s = b2[tid];
#pragma unroll 4
      for(int k = 0; k < NH; k += 4){
        const f32x4 hv = *(const f32x4*)(&h_f[k]);
        const f32x4 wv = *(const f32x4*)(w2r + k);
        s += hv[0] * wv[0] + hv[1] * wv[1] + hv[2] * wv[2] + hv[3] * wv[3];
      }
      u_lds[tid] = s;
    }
    __syncthreads();

    // scores for l = tid and l = tid+256 (bf16x8 row loads)
    float a0, a1;
#pragma unroll
    for(int e = 0; e < 2; ++e){
      const int l = tid + e * 256;
      const u16* br = bl + (size_t)(l * NB + b) * NW;
      float p = 0.f;
#pragma unroll 2
      for(int w0 = 0; w0 < NW; w0 += 8){
        const bf16x8 bv = *(const bf16x8*)(br + w0);
#pragma unroll
        for(int q = 0; q < 8; ++q)
          p += vt_lds[w0 + q] * tanh_(bf2f((u16)bv[q]) + u_lds[w0 + q]);
      }
      if(e == 0) a0 = p + vtbf; else a1 = p + vtbf;
    }

    // log-softmax over L = 512 (2 values per thread, block-wide reduction)
    float mx = fmaxf(a0, a1);
#pragma unroll
    for(int off = 32; off > 0; off >>= 1) mx = fmaxf(mx, __shfl_xor(mx, off, 64));
    if(lane == 0) red[wvl] = mx;
    __syncthreads();
    mx = fmaxf(fmaxf(red[0], red[1]), fmaxf(red[2], red[3]));
    float es = __expf(a0 - mx) + __expf(a1 - mx);
#pragma unroll
    for(int off = 32; off > 0; off >>= 1) es += __shfl_xor(es, off, 64);
    if(lane == 0) red[4 + wvl] = es;
    __syncthreads();
    const float lse = mx + logf(red[4] + red[5] + red[6] + red[7]);
    out[((size_t)tid * NB + b) * NT + t]         = a0 - lse;
    out[((size_t)(tid + 256) * NB + b) * NT + t] = a1 - lse;
    __syncthreads();
  }
  burn_sink(bacc);
}

// ---------------------------------------------------------------------------
extern "C" void kernel_launch(void* const* d_in, const int* in_sizes, int n_in,
                              void* d_out, int out_size, void* d_ws, size_t ws_size,
                              hipStream_t stream)
{
  (void)in_sizes; (void)n_in; (void)out_size; (void)ws_size;
  const int*   ids  = (const int*)d_in[0];
  const float* emb  = (const float*)d_in[1];
  const float* eWih = (const float*)d_in[2];
  const float* eWhh = (const float*)d_in[3];
  const float* ebih = (const float*)d_in[4];
  const float* ebhh = (const float*)d_in[5];
  /* d_in[6] = dec_Wih: unused (decoder input is identically zero) */
  const float* dWhh = (const float*)d_in[7];
  const float* dbih = (const float*)d_in[8];
  const float* dbhh = (const float*)d_in[9];
  const float* W1   = (const float*)d_in[10];
  const float* b1   = (const float*)d_in[11];
  const float* W2   = (const float*)d_in[12];
  const float* b2   = (const float*)d_in[13];
  const float* vt   = (const float*)d_in[14];
  const float* vtb  = (const float*)d_in[15];
  const float* h0   = (const float*)d_in[16];

  // workspace ~28.5 MB. X = bf16 emb during enc, then dec's 64 write-once h
  // slots (hdX; stale emb bf16 has bit14 clear for |v|<2 -> stamps valid
  // without pre-zeroing). hroll = enc's 16-deep h ring (slot 15 = h_511
  // feeds dec c0). flags = enc doorbells. cnt[64..67] = per-XCD enc-done.
  char* ws = (char*)d_ws;
  u16* bl     = (u16*)ws; ws += (size_t)NL * NB * NW * 2;    // blend1 bf16  16.78 MB
  u16* hroll  = (u16*)ws; ws += (size_t)RS * NBNH * 2;       // h ring       1.05 MB
  u16* X      = (u16*)ws; ws += (size_t)10000 * NE * 2;      // emb_b / hdec 5.12 MB
  u16* eWih_b = (u16*)ws; ws += (size_t)4 * NH * NE * 2;     // 1.05 MB
  u16* eWhh_b = (u16*)ws; ws += (size_t)4 * NH * NH * 2;     // 2.10 MB
  u16* dWhh_b = (u16*)ws; ws += (size_t)4 * NH * NH * 2;     // 2.10 MB
  u16* W1_b   = (u16*)ws; ws += (size_t)NW * NH * 2;         // 0.26 MB
  u32* cnt    = (u32*)ws; ws += 1024;                        // rank/done counters
  u32* flags  = (u32*)ws; ws += (size_t)4 * RS * 32 * 4;     // doorbells 8 KB

  // ring + flags pre-filled with phase-1 pattern; counters zeroed
  hipLaunchKernelGGL(fill_kernel, dim3((RS * NBNH / 2) / 256), dim3(256), 0, stream,
                     (u32*)hroll, 0x40004000u);
  hipLaunchKernelGGL(fill_kernel, dim3(8), dim3(256), 0, stream, flags, 1u);
  hipLaunchKernelGGL(fill_kernel, dim3(1), dim3(256), 0, stream, cnt, 0u);
  hipLaunchKernelGGL(cvt_kernel, dim3(10000), dim3(256), 0, stream, emb,  X,      10000 * NE);
  hipLaunchKernelGGL(cvt_kernel, dim3(2048),  dim3(256), 0, stream, eWih, eWih_b, 4 * NH * NE);
  hipLaunchKernelGGL(cvt_kernel, dim3(4096),  dim3(256), 0, stream, eWhh, eWhh_b, 4 * NH * NH);
  hipLaunchKernelGGL(cvt_kernel, dim3(4096),  dim3(256), 0, stream, dWhh, dWhh_b, 4 * NH * NH);
  hipLaunchKernelGGL(cvt_kernel, dim3(512),   dim3(256), 0, stream, W1,   W1_b,   NW * NH);

  // 90 KB dynamic LDS -> 1 block/CU -> 256-block grid is a bijection onto
  // CUs (enc: XCD pigeonhole; dec: producer/worker isolation per CU)
  hipLaunchKernelGGL(enc_kernel, dim3(256), dim3(256), 92160, stream,
                     ids, X, eWih_b, eWhh_b, ebih, ebhh, W1_b, b1, hroll, bl, cnt, flags);
  hipLaunchKernelGGL(dec_kernel, dim3(256), dim3(256), 92160, stream,
                     dWhh_b, dbih, dbhh, W2, b2, vt, vtb, bl, hroll, h0, X,
                     (float*)d_out);
}

// Round 14
// 3541.302 us; speedup vs baseline: 1.2248x; 1.1862x over previous
//
#include <hip/hip_runtime.h>

#define NB 64      // batch
#define NL 512     // seq len
#define NT 64      // answer len
#define NH 512     // hidden
#define NE 256     // emb dim
#define NW 256     // attention weight dim
#define NBNH (NB * NH)
#define RS 16      // h-ring depth (slots); phase stamp = (t>>4)&1
#define FPAD 16    // flags padded to one per 64B line (16 u32)

typedef __attribute__((ext_vector_type(8))) short bf16x8;
typedef __attribute__((ext_vector_type(4))) float f32x4;
typedef unsigned short u16;
typedef unsigned int u32;
typedef unsigned long long u64;

#define STM 0x4000400040004000ull   // bit14 of each u16 (never set in bf16 of |v|<2)
#define CLRM 0xBFFFBFFFBFFFBFFFull

__device__ __forceinline__ float bf2f(u16 v){
  union { u32 u; float f; } x; x.u = ((u32)v) << 16; return x.f;
}
__device__ __forceinline__ u16 f2bf(float f){
  union { float f; u32 u; } x; x.f = f;
  return (u16)((x.u + 0x7FFFu + ((x.u >> 16) & 1u)) >> 16);
}
__device__ __forceinline__ float sigm(float x){ return 1.f / (1.f + __expf(-x)); }
__device__ __forceinline__ float tanh_(float x){ float e = __expf(2.f * x); return 1.f - 2.f / (e + 1.f); }

// agent-scope load: bypasses L1, reads the local-XCD L2 (R8 FETCH evidence:
// polls are L2 hits under workgroup-scope publishes)
__device__ __forceinline__ u64 ald64(const u64* p){
  return __hip_atomic_load(p, __ATOMIC_RELAXED, __HIP_MEMORY_SCOPE_AGENT);
}
__device__ __forceinline__ u32 ald32(const u32* p){
  return __hip_atomic_load(p, __ATOMIC_RELAXED, __HIP_MEMORY_SCOPE_AGENT);
}
// agent-scope store: pushes to the device coherence point (cross-XCD safe;
// dec producers only — R9/R13 proved it regresses the in-XCD enc exchange)
__device__ __forceinline__ void ast64(u64* p, u64 v){
  __hip_atomic_store(p, v, __ATOMIC_RELAXED, __HIP_MEMORY_SCOPE_AGENT);
}
__device__ __forceinline__ void ast32(u32* p, u32 v){
  __hip_atomic_store(p, v, __ATOMIC_RELAXED, __HIP_MEMORY_SCOPE_AGENT);
}
// workgroup-scope store: plain store, write-through L1 -> LOCAL L2.
// Publish-mechanism ledger: plain=best(R8), +vmcnt fence=null(R7),
// agent=regression(R9), atomicExch=same regression(R13, atomics execute at
// L3). The residual exchange latency is NOT store mechanics — R14 tests
// reader-contention collapse on the polled lines instead.
__device__ __forceinline__ void st64(u64* p, u64 v){
  __hip_atomic_store(p, v, __ATOMIC_RELAXED, __HIP_MEMORY_SCOPE_WORKGROUP);
}
__device__ __forceinline__ void st32(u32* p, u32 v){
  __hip_atomic_store(p, v, __ATOMIC_RELAXED, __HIP_MEMORY_SCOPE_WORKGROUP);
}
__device__ __forceinline__ bf16x8 mk8(u64 a, u64 b){
  union { u64 q[2]; bf16x8 v; } u; u.q[0] = a; u.q[1] = b; return u.v;
}
__device__ __forceinline__ u32 xcc_id(){
  u32 x;
  asm volatile("s_getreg_b32 %0, hwreg(HW_REG_XCC_ID)" : "=s"(x));
  return x & 7u;
}
// MFMA burn while polling (keeps idle CUs hot; zero memory traffic)
__device__ __forceinline__ void burn32(f32x4* bacc, bf16x8 junk){
#pragma unroll
  for(int i = 0; i < 8; ++i)
#pragma unroll
    for(int g = 0; g < 4; ++g)
      bacc[g] = __builtin_amdgcn_mfma_f32_16x16x32_bf16(junk, junk, bacc[g], 0, 0, 0);
}
__device__ __forceinline__ void burn_sink(f32x4* bacc){
  asm volatile("" :: "v"(bacc[0][0]), "v"(bacc[1][0]), "v"(bacc[2][0]), "v"(bacc[3][0]));
}

__global__ void fill_kernel(u32* p, u32 v){
  p[blockIdx.x * 256 + threadIdx.x] = v;
}

// fp32 -> bf16 (round-to-nearest-even)
__global__ void cvt_kernel(const float* __restrict__ src, u16* __restrict__ dst, int n){
  const int i = blockIdx.x * 256 + threadIdx.x;
  if(i < n) dst[i] = f2bf(src[i]);
}

// ---------------------------------------------------------------------------
// Encoder, R8 base + CONTENTION TAMING. R13 closed the publish ledger (all
// store mechanisms tested; plain workgroup best). Remaining suspect: ~80
// waves/XCD spin with NO backoff on the same 1-2 flag cache lines, so the
// producer's doorbell store queues behind the reader storm (~N_readers x
// service = the measured ~10K-cycle D). Changes: (1) flags padded to one
// per 64B line (readers spread across 16+ L2 banks); (2) s_sleep backoff
// in every spin loop (5-10x lower poll issue rate).
// ---------------------------------------------------------------------------
__global__ void __launch_bounds__(256, 1) enc_kernel(
    const int* __restrict__ ids, const u16* __restrict__ emb,
    const u16* __restrict__ Wih, const u16* __restrict__ Whh,
    const float* __restrict__ bih, const float* __restrict__ bhh,
    const u16* __restrict__ W1,  const float* __restrict__ b1,
    u16* hroll, u16* bl, u32* cnt, u32* flags)
{
  extern __shared__ char dynsm[];         // 90 KB reserved (1 block/CU forcing)
  f32x4* pacc = (f32x4*)dynsm;            // [2 buf][2 pair][4 gate][64 lane]
  __shared__ u32 srank;

  const int lane = threadIdx.x & 63;
  const int wvl  = threadIdx.x >> 6;      // 0..3
  const int col  = lane & 15;
  const int quad = lane >> 4;

  const u32 xcd = xcc_id();
  if(xcd >= 4){
    // ---------------- burner: keep the clock domain hot ----------------
    f32x4 bacc[4];
#pragma unroll
    for(int g = 0; g < 4; ++g) bacc[g] = (f32x4){0.f, 0.f, 0.f, 0.f};
    const bf16x8 junk = {0, 0, 0, 0, 0, 0, 0, 0};
    const u32* dp = cnt + 64 + (xcd & 3);
    for(;;){
      if(ald32(dp) != 0u) break;
      burn32(bacc, junk); burn32(bacc, junk);
      burn32(bacc, junk); burn32(bacc, junk);
    }
    burn_sink(bacc);
    return;
  }
  if(threadIdx.x == 0) srank = atomicAdd(&cnt[xcd], 1u);
  __syncthreads();
  const u32 rank = srank;
  const int btile = (int)xcd;
  u32* fbase = flags + (size_t)xcd * (RS * 32 * FPAD);  // [slot][mtile][pad16]

  if(rank >= 16){
    if(rank >= 32) return;
    f32x4 bacc[4];
#pragma unroll
    for(int g = 0; g < 4; ++g) bacc[g] = (f32x4){0.f, 0.f, 0.f, 0.f};
    const bf16x8 junk = {0, 0, 0, 0, 0, 0, 0, 0};
    if(wvl != 0){
      // extra worker waves: burn until this XCD's producers finish
      const u32* dp = cnt + 64 + xcd;
      for(;;){
        if(ald32(dp) != 0u) break;
        burn32(bacc, junk); burn32(bacc, junk);
        burn32(bacc, junk); burn32(bacc, junk);
      }
      burn_sink(bacc);
      return;
    }
    // ---------------- blend1 worker: cols [ (rank-16)*16, +16 ) ----------------
    const int n1 = ((int)rank - 16) * 16 + col;
    bf16x8 w1f[16];                       // W1 row n1, register-cached
    const u16* w1p = W1 + (size_t)n1 * NH + quad * 8;
#pragma unroll
    for(int i = 0; i < 16; ++i) w1f[i] = *(const bf16x8*)(w1p + 32 * i);
    const float b1f = b1[n1];
    const int arow = btile * 16 + col;    // h row this lane holds as A-frag

    for(int t = 0; t < NL; ++t){
      const int slot = t & (RS - 1);
      const u32 fwant = (u32)((t >> 4) & 1);
      // flag poll: lane m polls mtile m's padded line; sleep+burn backoff
      {
        const u32* fp = fbase + (size_t)(slot * 32 + (lane & 31)) * FPAD;
        for(;;){
          const u32 f = ald32(fp);
          if(__ballot(f == fwant) == ~0ull) break;
          __builtin_amdgcn_s_sleep(2);
          burn32(bacc, junk);
        }
      }
      const u16* ha = hroll + (size_t)slot * NBNH + (size_t)arow * NH + quad * 8;
      const u64 want = fwant ? STM : 0ull;
      u64 hw[32];
      for(;;){                            // verify (flag may race data: retry)
        bool ok = true;
#pragma unroll
        for(int i = 0; i < 16; ++i){
          const u64* p = (const u64*)(ha + 32 * i);
          hw[2 * i]     = ald64(p);
          hw[2 * i + 1] = ald64(p + 1);
          ok = ok && ((hw[2 * i] & STM) == want) && ((hw[2 * i + 1] & STM) == want);
        }
        if(__ballot(ok) == ~0ull) break;
        __builtin_amdgcn_s_sleep(1);
      }
      f32x4 a2 = {0.f, 0.f, 0.f, 0.f};
#pragma unroll
      for(int i = 0; i < 16; ++i)
        a2 = __builtin_amdgcn_mfma_f32_16x16x32_bf16(
               mk8(hw[2 * i] & CLRM, hw[2 * i + 1] & CLRM), w1f[i], a2, 0, 0, 0);
#pragma unroll
      for(int r = 0; r < 4; ++r){
        const int b = btile * 16 + quad * 4 + r;
        bl[((size_t)t * NB + b) * NW + n1] = f2bf(a2[r] + b1f);
      }
    }
    burn_sink(bacc);
    return;
  }

  // ------------------------------ producer ------------------------------
  const int mtile  = (int)rank * 2 + (wvl >> 1);   // 0..31
  const int khalf  = wvl & 1;                      // K-half of the recurrence
  const int pairid = wvl >> 1;                     // LDS pair slot
  const bool lowerw = (khalf == 0);
  const int j  = mtile * 16 + col;                 // hidden index within gate
  const int ab = btile * 16 + col;                 // A-row (batch) this lane loads

  float bias[4];
  const u16* wx[4];
  bf16x8 whr[8][4];                       // Whh fragments, THIS K-half only
#pragma unroll
  for(int g = 0; g < 4; ++g){
    const int row = g * NH + j;           // PyTorch gate order i,f,g,o
    bias[g] = bih[row] + bhh[row];
    wx[g] = Wih + (size_t)row * NE + khalf * 128 + quad * 8;
    const u16* whp = Whh + (size_t)row * NH + khalf * 256 + quad * 8;
#pragma unroll
    for(int i = 0; i < 8; ++i)
      whr[i][g] = *(const bf16x8*)(whp + 32 * i);
  }
  const int* idp = ids + ab * NL;         // ids is [B, L]
  float creg[4] = {0.f, 0.f, 0.f, 0.f};   // cell state (lower wave only live)

  u64 hb[16];                             // h K-half fragment
  f32x4 acc[4];

  // x-part of t=0 (this wave's K-half of NE)
  {
    const u16* xr = emb + (size_t)idp[0] * NE + khalf * 128 + quad * 8;
#pragma unroll
    for(int g = 0; g < 4; ++g) acc[g] = (f32x4){0.f, 0.f, 0.f, 0.f};
#pragma unroll
    for(int k0 = 0; k0 < 128; k0 += 32){
      const bf16x8 af = *(const bf16x8*)(xr + k0);
#pragma unroll
      for(int g = 0; g < 4; ++g)
        acc[g] = __builtin_amdgcn_mfma_f32_16x16x32_bf16(af, *(const bf16x8*)(wx[g] + k0), acc[g], 0, 0, 0);
    }
  }

  for(int t = 0; t < NL; ++t){
    // h-part for step t (hb = K-half of h_{t-1}, polled last iteration)
    if(t > 0){
#pragma unroll
      for(int i = 0; i < 8; ++i){
        const bf16x8 af = mk8(hb[2 * i], hb[2 * i + 1]);
#pragma unroll
        for(int g = 0; g < 4; ++g)
          acc[g] = __builtin_amdgcn_mfma_f32_16x16x32_bf16(af, whr[i][g], acc[g], 0, 0, 0);
      }
    }
    // issue next-step emb loads NOW: latency hides under barrier+epilogue
    bf16x8 xa0, xa1, xa2, xa3;
    const u16* xr = (t + 1 < NL) ? (emb + (size_t)idp[t + 1] * NE + khalf * 128 + quad * 8) : emb;
    xa0 = *(const bf16x8*)(xr);
    xa1 = *(const bf16x8*)(xr + 32);
    xa2 = *(const bf16x8*)(xr + 64);
    xa3 = *(const bf16x8*)(xr + 96);

    const int slot = t & (RS - 1);
    const u32 fphase = (u32)((t >> 4) & 1);

    // K-half merge: upper writes partial acc; one barrier; lower sums + epilogue
    if(!lowerw){
#pragma unroll
      for(int g = 0; g < 4; ++g)
        pacc[(((t & 1) * 2 + pairid) * 4 + g) * 64 + lane] = acc[g];
    }
    __syncthreads();
    if(lowerw){
#pragma unroll
      for(int g = 0; g < 4; ++g){
        const f32x4 pa = pacc[(((t & 1) * 2 + pairid) * 4 + g) * 64 + lane];
        acc[g][0] += pa[0]; acc[g][1] += pa[1]; acc[g][2] += pa[2]; acc[g][3] += pa[3];
      }
      const u64 pst = fphase ? STM : 0ull;
      u16* ho = hroll + (size_t)slot * NBNH;
#pragma unroll
      for(int r = 0; r < 4; ++r){
        const float gi = acc[0][r] + bias[0];
        const float gf = acc[1][r] + bias[1];
        const float gg = acc[2][r] + bias[2];
        const float go = acc[3][r] + bias[3];
        creg[r] = sigm(gf) * creg[r] + sigm(gi) * tanh_(gg);
        const u32 raw  = (u32)f2bf(sigm(go) * tanh_(creg[r]));
        const u32 pair = raw | (((u32)__shfl_xor((int)raw, 1, 64)) << 16);
        const u32 hi   = (u32)__shfl_xor((int)pair, 2, 64);
        if((col & 3) == 0){
          const int row = btile * 16 + quad * 4 + r;
          st64((u64*)(ho + (size_t)row * NH + mtile * 16 + col),
               ((u64)pair | ((u64)hi << 32)) | pst);
        }
      }
      // flag doorbell on its own 64B line (advisory; stamps = correctness)
      if(lane == 0) st32(fbase + (size_t)(slot * 32 + mtile) * FPAD, fphase);
    }
    if(t + 1 < NL){
      // x-part of t+1 from the pre-issued registers
#pragma unroll
      for(int g = 0; g < 4; ++g) acc[g] = (f32x4){0.f, 0.f, 0.f, 0.f};
#pragma unroll
      for(int g = 0; g < 4; ++g){
        acc[g] = __builtin_amdgcn_mfma_f32_16x16x32_bf16(xa0, *(const bf16x8*)(wx[g]),      acc[g], 0, 0, 0);
        acc[g] = __builtin_amdgcn_mfma_f32_16x16x32_bf16(xa1, *(const bf16x8*)(wx[g] + 32), acc[g], 0, 0, 0);
        acc[g] = __builtin_amdgcn_mfma_f32_16x16x32_bf16(xa2, *(const bf16x8*)(wx[g] + 64), acc[g], 0, 0, 0);
        acc[g] = __builtin_amdgcn_mfma_f32_16x16x32_bf16(xa3, *(const bf16x8*)(wx[g] + 96), acc[g], 0, 0, 0);
      }
      // flag poll: lane m (m<16) polls mtile khalf*16+m's padded line;
      // s_sleep backoff after each miss (reader-storm taming)
      {
        const u32* fp = fbase + (size_t)(slot * 32 + khalf * 16 + (lane & 15)) * FPAD;
        for(;;){
          const u32 f = ald32(fp);
          if(__ballot(f == fphase) == ~0ull) break;
          __builtin_amdgcn_s_sleep(1);
        }
      }
      // data load + stamp verify (retry if flag raced data)
      {
        const u16* ha = hroll + (size_t)slot * NBNH + (size_t)ab * NH + khalf * 256 + quad * 8;
        const u64 want = fphase ? STM : 0ull;
        for(;;){
          bool ok = true;
#pragma unroll
          for(int i = 0; i < 8; ++i){
            const u64* p = (const u64*)(ha + 32 * i);
            hb[2 * i]     = ald64(p);
            hb[2 * i + 1] = ald64(p + 1);
            ok = ok && ((hb[2 * i] & STM) == want) && ((hb[2 * i + 1] & STM) == want);
          }
          if(__ballot(ok) == ~0ull) break;
          __builtin_amdgcn_s_sleep(1);
        }
#pragma unroll
        for(int i = 0; i < 16; ++i) hb[i] &= CLRM;
      }
    }
  }
  // signal burners: this XCD's recurrence is done (agent scope, cross-XCD)
  if(rank == 0 && threadIdx.x == 0) ast32(cnt + 64 + (u32)xcd, 1u);
}

// ---------------------------------------------------------------------------
// Decoder (R8 structure + backoff): blocks 0..63 = producers (direct
// agent-scope stores into 64 write-once stamped hdX slots; poll slot t-1
// with s_sleep backoff), blocks 64..255 = 192 attention workers (burn +
// s_sleep backoff — their polls hammer the very lines producers store).
// c0 = enc h_511 (hroll slot 15).
// ---------------------------------------------------------------------------
__global__ void __launch_bounds__(256, 1) dec_kernel(
    const u16* __restrict__ Whh, const float* __restrict__ bih, const float* __restrict__ bhh,
    const float* __restrict__ W2, const float* __restrict__ b2,
    const float* __restrict__ vt, const float* __restrict__ vtb,
    const u16* __restrict__ bl,  const u16* __restrict__ hroll,
    const float* __restrict__ h0f,
    u16* hdX, float* __restrict__ out)
{
  extern __shared__ char dynsm[];
  f32x4* pacc = (f32x4*)dynsm;            // [2][2][4][64]
  __shared__ __align__(16) float h_f[NH];
  __shared__ __align__(16) float u_lds[NW];
  __shared__ __align__(16) float vt_lds[NW];
  __shared__ float red[8];

  const int tid  = threadIdx.x;
  const int lane = tid & 63;
  const int wvl  = tid >> 6;
  const int col  = lane & 15;
  const int quad = lane >> 4;

  if(blockIdx.x < 64){
    // ------------------------------ producer ------------------------------
    const int btile  = (int)blockIdx.x >> 4;
    const int rank   = (int)blockIdx.x & 15;
    const int mtile  = rank * 2 + (wvl >> 1);
    const int khalf  = wvl & 1;
    const int pairid = wvl >> 1;
    const bool lowerw = (khalf == 0);
    const int j  = mtile * 16 + col;
    const int ab = btile * 16 + col;

    float bias[4];
    bf16x8 whr[8][4];
#pragma unroll
    for(int g = 0; g < 4; ++g){
      const int row = g * NH + j;
      bias[g] = bih[row] + bhh[row];
      const u16* whp = Whh + (size_t)row * NH + khalf * 256 + quad * 8;
#pragma unroll
      for(int i = 0; i < 8; ++i)
        whr[i][g] = *(const bf16x8*)(whp + 32 * i);
    }
    float creg[4] = {0.f, 0.f, 0.f, 0.f};
    if(lowerw){
      // c0 = enc h_511 (hroll slot 15; stamp bits set -> mask)
#pragma unroll
      for(int r = 0; r < 4; ++r){
        const int ci = (btile * 16 + quad * 4 + r) * NH + j;
        creg[r] = bf2f((u16)(hroll[(size_t)15 * NBNH + ci] & 0xBFFFu));
      }
    }
    u64 hb[16];
    f32x4 acc[4];

    // t=0 h-part: h_{-1} = h0 (fp32), this wave's K-half
    {
      const float* hp = h0f + (size_t)ab * NH + khalf * 256 + quad * 8;
#pragma unroll
      for(int g = 0; g < 4; ++g) acc[g] = (f32x4){0.f, 0.f, 0.f, 0.f};
#pragma unroll
      for(int i = 0; i < 8; ++i){
        const f32x4 a0 = *(const f32x4*)(hp + 32 * i);
        const f32x4 a1 = *(const f32x4*)(hp + 32 * i + 4);
        bf16x8 af;
#pragma unroll
        for(int q = 0; q < 4; ++q){ af[q] = (short)f2bf(a0[q]); af[q + 4] = (short)f2bf(a1[q]); }
#pragma unroll
        for(int g = 0; g < 4; ++g)
          acc[g] = __builtin_amdgcn_mfma_f32_16x16x32_bf16(af, whr[i][g], acc[g], 0, 0, 0);
      }
    }

    for(int t = 0; t < NT; ++t){
      if(t > 0){
#pragma unroll
        for(int g = 0; g < 4; ++g) acc[g] = (f32x4){0.f, 0.f, 0.f, 0.f};
#pragma unroll
        for(int i = 0; i < 8; ++i){
          const bf16x8 af = mk8(hb[2 * i], hb[2 * i + 1]);
#pragma unroll
          for(int g = 0; g < 4; ++g)
            acc[g] = __builtin_amdgcn_mfma_f32_16x16x32_bf16(af, whr[i][g], acc[g], 0, 0, 0);
        }
      }
      if(!lowerw){
#pragma unroll
        for(int g = 0; g < 4; ++g)
          pacc[(((t & 1) * 2 + pairid) * 4 + g) * 64 + lane] = acc[g];
      }
      __syncthreads();
      if(lowerw){
#pragma unroll
        for(int g = 0; g < 4; ++g){
          const f32x4 pa = pacc[(((t & 1) * 2 + pairid) * 4 + g) * 64 + lane];
          acc[g][0] += pa[0]; acc[g][1] += pa[1]; acc[g][2] += pa[2]; acc[g][3] += pa[3];
        }
        // epilogue: h_t stamped -> write-once slot t (agent scope, direct)
        u16* hn = hdX + (size_t)t * NBNH;
#pragma unroll
        for(int r = 0; r < 4; ++r){
          const float gi = acc[0][r] + bias[0];
          const float gf = acc[1][r] + bias[1];
          const float gg = acc[2][r] + bias[2];
          const float go = acc[3][r] + bias[3];
          creg[r] = sigm(gf) * creg[r] + sigm(gi) * tanh_(gg);
          const u32 stv  = (u32)f2bf(sigm(go) * tanh_(creg[r])) | 0x4000u;
          const u32 pair = stv | (((u32)__shfl_xor((int)stv, 1, 64)) << 16);
          const u32 hi   = (u32)__shfl_xor((int)pair, 2, 64);
          if((col & 3) == 0){
            const int row = btile * 16 + quad * 4 + r;
            ast64((u64*)(hn + (size_t)row * NH + mtile * 16 + col),
                  (u64)pair | ((u64)hi << 32));
          }
        }
      }
      if(t + 1 < NT){
        // poll slot t directly (write-once, stamp in data); sleep backoff
        const u16* ha = hdX + (size_t)t * NBNH + (size_t)ab * NH + khalf * 256 + quad * 8;
        for(;;){
          bool ok = true;
#pragma unroll
          for(int i = 0; i < 8; ++i){
            const u64* p = (const u64*)(ha + 32 * i);
            hb[2 * i]     = ald64(p);
            hb[2 * i + 1] = ald64(p + 1);
            ok = ok && ((hb[2 * i] & STM) == STM) && ((hb[2 * i + 1] & STM) == STM);
          }
          if(__ballot(ok) == ~0ull) break;
          __builtin_amdgcn_s_sleep(1);
        }
#pragma unroll
        for(int i = 0; i < 16; ++i) hb[i] &= CLRM;
      }
    }
    return;
  }

  // ------------------------- attention worker path -------------------------
  const int wid = (int)blockIdx.x - 64;   // 0..191

  vt_lds[tid] = vt[tid];
  const float vtbf = vtb[0];
  __syncthreads();

  f32x4 bacc[4];
#pragma unroll
  for(int g = 0; g < 4; ++g) bacc[g] = (f32x4){0.f, 0.f, 0.f, 0.f};
  const bf16x8 junk = {0, 0, 0, 0, 0, 0, 0, 0};

  for(int tk = wid; tk < NT * NB; tk += 192){
    const int t = tk >> 6;
    const int b = tk & 63;

    // poll slot t row b (stamped bf16); burn + sleep backoff so worker
    // polls don't queue ahead of the producers' stores to these lines
    {
      const u32* hp = (const u32*)(hdX + (size_t)t * NBNH + (size_t)b * NH);
      u32 v;
      for(;;){
        v = ald32(hp + tid);
        const int ok = ((v & 0x40004000u) == 0x40004000u) ? 1 : 0;
        if(__syncthreads_and(ok)) break;
        __builtin_amdgcn_s_sleep(2);
        burn32(bacc, junk);
      }
      h_f[2 * tid]     = bf2f((u16)(v & 0xBFFFu));
      h_f[2 * tid + 1] = bf2f((u16)((v >> 16) & 0xBFFFu));
    }
    __syncthreads();

    // u[n] = b2[n] + h . W2[n,:]   (h broadcast from LDS, f32x4 loads)
    {
      const float* w2r = W2 + (size_t)tid * NH;
      float s = b2[tid];
#pragma unroll 4
      for(int k = 0; k < NH; k += 4){
        const f32x4 hv = *(const f32x4*)(&h_f[k]);
        const f32x4 wv = *(const f32x4*)(w2r + k);
        s += hv[0] * wv[0] + hv[1] * wv[1] + hv[2] * wv[2] + hv[3] * wv[3];
      }
      u_lds[tid] = s;
    }
    __syncthreads();

    // scores for l = tid and l = tid+256 (bf16x8 row loads)
    float a0, a1;
#pragma unroll
    for(int e = 0; e < 2; ++e){
      const int l = tid + e * 256;
      const u16* br = bl + (size_t)(l * NB + b) * NW;
      float p = 0.f;
#pragma unroll 2
      for(int w0 = 0; w0 < NW; w0 += 8){
        const bf16x8 bv = *(const bf16x8*)(br + w0);
#pragma unroll
        for(int q = 0; q < 8; ++q)
          p += vt_lds[w0 + q] * tanh_(bf2f((u16)bv[q]) + u_lds[w0 + q]);
      }
      if(e == 0) a0 = p + vtbf; else a1 = p + vtbf;
    }

    // log-softmax over L = 512 (2 values per thread, block-wide reduction)
    float mx = fmaxf(a0, a1);
#pragma unroll
    for(int off = 32; off > 0; off >>= 1) mx = fmaxf(mx, __shfl_xor(mx, off, 64));
    if(lane == 0) red[wvl] = mx;
    __syncthreads();
    mx = fmaxf(fmaxf(red[0], red[1]), fmaxf(red[2], red[3]));
    float es = __expf(a0 - mx) + __expf(a1 - mx);
#pragma unroll
    for(int off = 32; off > 0; off >>= 1) es += __shfl_xor(es, off, 64);
    if(lane == 0) red[4 + wvl] = es;
    __syncthreads();
    const float lse = mx + logf(red[4] + red[5] + red[6] + red[7]);
    out[((size_t)tid * NB + b) * NT + t]         = a0 - lse;
    out[((size_t)(tid + 256) * NB + b) * NT + t] = a1 - lse;
    __syncthreads();
  }
  burn_sink(bacc);
}

// ---------------------------------------------------------------------------
extern "C" void kernel_launch(void* const* d_in, const int* in_sizes, int n_in,
                              void* d_out, int out_size, void* d_ws, size_t ws_size,
                              hipStream_t stream)
{
  (void)in_sizes; (void)n_in; (void)out_size; (void)ws_size;
  const int*   ids  = (const int*)d_in[0];
  const float* emb  = (const float*)d_in[1];
  const float* eWih = (const float*)d_in[2];
  const float* eWhh = (const float*)d_in[3];
  const float* ebih = (const float*)d_in[4];
  const float* ebhh = (const float*)d_in[5];
  /* d_in[6] = dec_Wih: unused (decoder input is identically zero) */
  const float* dWhh = (const float*)d_in[7];
  const float* dbih = (const float*)d_in[8];
  const float* dbhh = (const float*)d_in[9];
  const float* W1   = (const float*)d_in[10];
  const float* b1   = (const float*)d_in[11];
  const float* W2   = (const float*)d_in[12];
  const float* b2   = (const float*)d_in[13];
  const float* vt   = (const float*)d_in[14];
  const float* vtb  = (const float*)d_in[15];
  const float* h0   = (const float*)d_in[16];

  // workspace ~28.7 MB. X = bf16 emb during enc, then dec's 64 write-once h
  // slots (hdX; stale emb bf16 has bit14 clear for |v|<2 -> stamps valid
  // without pre-zeroing). hroll = enc's 16-deep h ring (slot 15 = h_511
  // feeds dec c0). flags = enc doorbells, PADDED one per 64B line (128 KB).
  // cnt[64..67] = per-XCD enc-done.
  char* ws = (char*)d_ws;
  u16* bl     = (u16*)ws; ws += (size_t)NL * NB * NW * 2;    // blend1 bf16  16.78 MB
  u16* hroll  = (u16*)ws; ws += (size_t)RS * NBNH * 2;       // h ring       1.05 MB
  u16* X      = (u16*)ws; ws += (size_t)10000 * NE * 2;      // emb_b / hdec 5.12 MB
  u16* eWih_b = (u16*)ws; ws += (size_t)4 * NH * NE * 2;     // 1.05 MB
  u16* eWhh_b = (u16*)ws; ws += (size_t)4 * NH * NH * 2;     // 2.10 MB
  u16* dWhh_b = (u16*)ws; ws += (size_t)4 * NH * NH * 2;     // 2.10 MB
  u16* W1_b   = (u16*)ws; ws += (size_t)NW * NH * 2;         // 0.26 MB
  u32* cnt    = (u32*)ws; ws += 1024;                        // rank/done counters
  u32* flags  = (u32*)ws; ws += (size_t)4 * RS * 32 * FPAD * 4;  // doorbells 128 KB

  // ring + flags pre-filled with phase-1 pattern; counters zeroed
  hipLaunchKernelGGL(fill_kernel, dim3((RS * NBNH / 2) / 256), dim3(256), 0, stream,
                     (u32*)hroll, 0x40004000u);
  hipLaunchKernelGGL(fill_kernel, dim3((4 * RS * 32 * FPAD) / 256), dim3(256), 0, stream,
                     flags, 1u);
  hipLaunchKernelGGL(fill_kernel, dim3(1), dim3(256), 0, stream, cnt, 0u);
  hipLaunchKernelGGL(cvt_kernel, dim3(10000), dim3(256), 0, stream, emb,  X,      10000 * NE);
  hipLaunchKernelGGL(cvt_kernel, dim3(2048),  dim3(256), 0, stream, eWih, eWih_b, 4 * NH * NE);
  hipLaunchKernelGGL(cvt_kernel, dim3(4096),  dim3(256), 0, stream, eWhh, eWhh_b, 4 * NH * NH);
  hipLaunchKernelGGL(cvt_kernel, dim3(4096),  dim3(256), 0, stream, dWhh, dWhh_b, 4 * NH * NH);
  hipLaunchKernelGGL(cvt_kernel, dim3(512),   dim3(256), 0, stream, W1,   W1_b,   NW * NH);

  // 90 KB dynamic LDS -> 1 block/CU -> 256-block grid is a bijection onto
  // CUs (enc: XCD pigeonhole; dec: producer/worker isolation per CU)
  hipLaunchKernelGGL(enc_kernel, dim3(256), dim3(256), 92160, stream,
                     ids, X, eWih_b, eWhh_b, ebih, ebhh, W1_b, b1, hroll, bl, cnt, flags);
  hipLaunchKernelGGL(dec_kernel, dim3(256), dim3(256), 92160, stream,
                     dWhh_b, dbih, dbhh, W2, b2, vt, vtb, bl, hroll, h0, X,
                     (float*)d_out);
}